// Round 12
// baseline (71.488 us; speedup 1.0000x reference)
//
#include <hip/hip_runtime.h>
#include <hip/hip_fp16.h>
#include <hip/hip_cooperative_groups.h>
#include <cstddef>

namespace cg = cooperative_groups;

#define BATCH 64
#define HW 512
#define RVAL (1.0f / 512.0f)   // r = c = 1/512, exact in fp32
#define EPS_ 1e-6f
#define MAXIT 100
#define NBLK 256               // == CU count: cooperative launch always fits
#define NTHR 1024              // 16 waves/block

typedef float f32x4 __attribute__((ext_vector_type(4)));

__device__ __forceinline__ unsigned h2u(__half2 h) {
    union { __half2 h; unsigned u; } c; c.h = h; return c.u;
}
__device__ __forceinline__ __half2 u2h(unsigned u) {
    union { unsigned u; __half2 h; } c; c.u = u; return c.h;
}

// LDS-resident-K Sinkhorn, low-latency exchange edition.
// K = exp(-M) cached once in LDS as fp16 (128 KB/block; error 2.4e-4 rel ->
// ~1.6e-9 abs on P, absmax stays at the fp32 floor 2.98e-8). Cross-block
// exchange (4 blocks/batch) is fence-free relaxed-atomic (round-9 proven)
// and barrier-minimal: publisher waves store + in-wave vmcnt(0) + flag
// bump (target 32 = 4 blocks x 8 waves); every wave's lane0 spins on the
// flag; the closing __syncthreads_or is the only other block barrier and
// also protects part[] reuse and the double-buffered v update.
__global__ __launch_bounds__(NTHR, 4)
void sinkhorn_lds2(const float* __restrict__ M, float* __restrict__ P,
                   float* __restrict__ colpart, int* __restrict__ bar,
                   int tail_mode) {
    const int tid  = threadIdx.x;
    const int bid  = blockIdx.x;
    const int b    = bid >> 2;     // batch (4 blocks per batch)
    const int slab = bid & 3;      // 128-row slab
    const int w    = tid >> 6;     // wave 0..15 (owns rows w*8..w*8+8)
    const int l    = tid & 63;     // lane: cols [4l,4l+4) and [256+4l,..)

    cg::grid_group grid = cg::this_grid();

    __shared__ unsigned K_lds[128][HW / 2];  // fp16 pairs, 128 KB
    __shared__ float    part[8][HW];         // 16 KB (two-step reduce)
    __shared__ float    v_lds[2][HW];        // 4 KB, double-buffered

    if (tid < HW) v_lds[0][tid] = 1.0f;
    __syncthreads();

    const f32x4* Mb =
        (const f32x4*)(M + ((size_t)b * HW + slab * 128) * HW);

    float u_loc[8];
    int cur = 0;
    for (int it = 0; it < MAXIT; ++it) {
        float4 v0 = *(const float4*)&v_lds[cur][l * 4];
        float4 v1 = *(const float4*)&v_lds[cur][256 + l * 4];
        float4 cp0 = make_float4(0.f, 0.f, 0.f, 0.f);
        float4 cp1 = make_float4(0.f, 0.f, 0.f, 0.f);

        if (it == 0) {
            // sweep 0: HBM (nontemporal) load, K=exp(-M)->LDS, fused marginals
#pragma unroll
            for (int rr = 0; rr < 8; ++rr) {
                const int row = w * 8 + rr;
                const f32x4* mp = Mb + (size_t)row * 128;
                f32x4 m0 = __builtin_nontemporal_load(mp + l);
                f32x4 m1 = __builtin_nontemporal_load(mp + 64 + l);
                float4 k0, k1;
                k0.x = __expf(-m0.x); k0.y = __expf(-m0.y);
                k0.z = __expf(-m0.z); k0.w = __expf(-m0.w);
                k1.x = __expf(-m1.x); k1.y = __expf(-m1.y);
                k1.z = __expf(-m1.z); k1.w = __expf(-m1.w);
                uint2 q0, q1;
                q0.x = h2u(__floats2half2_rn(k0.x, k0.y));
                q0.y = h2u(__floats2half2_rn(k0.z, k0.w));
                q1.x = h2u(__floats2half2_rn(k1.x, k1.y));
                q1.y = h2u(__floats2half2_rn(k1.z, k1.w));
                *(uint2*)&K_lds[row][2 * l]       = q0;
                *(uint2*)&K_lds[row][128 + 2 * l] = q1;
                float s = k0.x * v0.x + k0.y * v0.y + k0.z * v0.z + k0.w * v0.w
                        + k1.x * v1.x + k1.y * v1.y + k1.z * v1.z + k1.w * v1.w;
#pragma unroll
                for (int off = 32; off >= 1; off >>= 1)
                    s += __shfl_xor(s, off, 64);
                float u = RVAL / s;
                u_loc[rr] = u;
                cp0.x += u * k0.x; cp0.y += u * k0.y;
                cp0.z += u * k0.z; cp0.w += u * k0.w;
                cp1.x += u * k1.x; cp1.y += u * k1.y;
                cp1.z += u * k1.z; cp1.w += u * k1.w;
            }
        } else {
            // iteration sweep: K from LDS, zero global traffic
#pragma unroll
            for (int rr = 0; rr < 8; ++rr) {
                const int row = w * 8 + rr;
                uint2 q0 = *(const uint2*)&K_lds[row][2 * l];
                uint2 q1 = *(const uint2*)&K_lds[row][128 + 2 * l];
                float2 a0 = __half22float2(u2h(q0.x));
                float2 a1 = __half22float2(u2h(q0.y));
                float2 b0 = __half22float2(u2h(q1.x));
                float2 b1 = __half22float2(u2h(q1.y));
                float s = a0.x * v0.x + a0.y * v0.y + a1.x * v0.z + a1.y * v0.w
                        + b0.x * v1.x + b0.y * v1.y + b1.x * v1.z + b1.y * v1.w;
#pragma unroll
                for (int off = 32; off >= 1; off >>= 1)
                    s += __shfl_xor(s, off, 64);
                float u = RVAL / s;
                u_loc[rr] = u;
                cp0.x += u * a0.x; cp0.y += u * a0.y;
                cp0.z += u * a1.x; cp0.w += u * a1.y;
                cp1.x += u * b0.x; cp1.y += u * b0.y;
                cp1.z += u * b1.x; cp1.w += u * b1.y;
            }
        }

        // ---- two-step cross-wave column reduction into part[0..8) ----
        if (w < 8) {
            *(float4*)&part[w][l * 4]       = cp0;
            *(float4*)&part[w][256 + l * 4] = cp1;
        }
        __syncthreads();                     // barrier 1
        if (w >= 8) {
            float4 e0 = *(float4*)&part[w - 8][l * 4];
            float4 e1 = *(float4*)&part[w - 8][256 + l * 4];
            e0.x += cp0.x; e0.y += cp0.y; e0.z += cp0.z; e0.w += cp0.w;
            e1.x += cp1.x; e1.y += cp1.y; e1.z += cp1.z; e1.w += cp1.w;
            *(float4*)&part[w - 8][l * 4]       = e0;
            *(float4*)&part[w - 8][256 + l * 4] = e1;
        }
        __syncthreads();                     // barrier 2

        // ---- publisher waves 0..7: stripe sum + store + in-wave flag ----
        float* slot = colpart + ((size_t)((it & 1) * NBLK + bid)) * HW;
        int* bs = bar + b * MAXIT + it;
        if (w < 8) {
            const int col = w * 64 + l;
            float t = 0.f;
#pragma unroll
            for (int ww = 0; ww < 8; ++ww) t += part[ww][col];
            __hip_atomic_store(&slot[col], t, __ATOMIC_RELAXED,
                               __HIP_MEMORY_SCOPE_AGENT);
            asm volatile("s_waitcnt vmcnt(0)" ::: "memory");
            if (l == 0)
                __hip_atomic_fetch_add(bs, 1, __ATOMIC_RELAXED,
                                       __HIP_MEMORY_SCOPE_AGENT);
        }

        // ---- every wave spins independently until all 32 stripes landed ----
        if (l == 0) {
            while (__hip_atomic_load(bs, __ATOMIC_RELAXED,
                                     __HIP_MEMORY_SCOPE_AGENT) < 32)
                __builtin_amdgcn_s_sleep(1);
        }
        // lanes reconverge here; wave proceeds when its lane0 exits

        // ---- combine 4 slabs (fixed order); convergence; v -> other buffer --
        float tt = 0.f;
        int viol = 0;
        if (tid < HW) {
            const float* basep =
                colpart + ((size_t)((it & 1) * NBLK + b * 4)) * HW;
#pragma unroll
            for (int bb = 0; bb < 4; ++bb)
                tt += __hip_atomic_load(basep + bb * HW + tid, __ATOMIC_RELAXED,
                                        __HIP_MEMORY_SCOPE_AGENT);
            viol = fabsf(v_lds[cur][tid] * tt - RVAL) > EPS_;
            v_lds[cur ^ 1][tid] = RVAL / tt;   // speculative col-normalize
        }
        int any = __syncthreads_or(viol);    // barrier 3: break decision +
                                             // part[] reuse + v publish
        if (!any) break;                     // keep u_loc and v_lds[cur]
        cur ^= 1;
    }

    // Only when scratch aliases d_out's tail: rendezvous before P stores.
    if (tail_mode) grid.sync();

    // ---- final: P = diag(u) K diag(v), K from LDS, nontemporal stores ----
    float4 fv0 = *(const float4*)&v_lds[cur][l * 4];
    float4 fv1 = *(const float4*)&v_lds[cur][256 + l * 4];
    f32x4* Pb = (f32x4*)(P + ((size_t)b * HW + slab * 128) * HW);
#pragma unroll
    for (int rr = 0; rr < 8; ++rr) {
        const int row = w * 8 + rr;
        float u = u_loc[rr];
        uint2 q0 = *(const uint2*)&K_lds[row][2 * l];
        uint2 q1 = *(const uint2*)&K_lds[row][128 + 2 * l];
        float2 a0 = __half22float2(u2h(q0.x));
        float2 a1 = __half22float2(u2h(q0.y));
        float2 b0 = __half22float2(u2h(q1.x));
        float2 b1 = __half22float2(u2h(q1.y));
        f32x4 o0, o1;
        o0.x = u * a0.x * fv0.x; o0.y = u * a0.y * fv0.y;
        o0.z = u * a1.x * fv0.z; o0.w = u * a1.y * fv0.w;
        o1.x = u * b0.x * fv1.x; o1.y = u * b0.y * fv1.y;
        o1.z = u * b1.x * fv1.z; o1.w = u * b1.y * fv1.w;
        __builtin_nontemporal_store(o0, Pb + (size_t)row * 128 + l);
        __builtin_nontemporal_store(o1, Pb + (size_t)row * 128 + 64 + l);
    }
}

extern "C" void kernel_launch(void* const* d_in, const int* in_sizes, int n_in,
                              void* d_out, int out_size, void* d_ws, size_t ws_size,
                              hipStream_t stream) {
    const float* M = (const float*)d_in[0];
    float* P = (float*)d_out;

    const size_t CP_BYTES  = (size_t)2 * NBLK * HW * sizeof(float);  // 1 MB
    const size_t BAR_BYTES = (size_t)BATCH * MAXIT * sizeof(int);    // 25.6 KB
    const size_t NEED = CP_BYTES + BAR_BYTES;

    char* scratch;
    int tail_mode;
    if (ws_size >= NEED) {
        scratch = (char*)d_ws;
        tail_mode = 0;
    } else {
        // tail of d_out; P stores are gated by the post-loop grid.sync
        scratch = (char*)d_out + (size_t)out_size * sizeof(float) - NEED;
        tail_mode = 1;
    }
    float* colpart = (float*)scratch;
    int*   bar     = (int*)(scratch + CP_BYTES);

    hipMemsetAsync(bar, 0, BAR_BYTES, stream);

    void* args[] = { (void*)&M, (void*)&P, (void*)&colpart, (void*)&bar,
                     (void*)&tail_mode };
    hipLaunchCooperativeKernel((const void*)sinkhorn_lds2, dim3(NBLK),
                               dim3(NTHR), args, 0, stream);
}